// Round 1
// baseline (1085.236 us; speedup 1.0000x reference)
//
#include <hip/hip_runtime.h>

// proto-contrastive CE loss, fp32 baseline.
// features [N=1e6, D=128] f32, labels [N] i32, prototypes [C=150, D=128] f32 (pre-normalized).
// out[0] = mean_n( logsumexp_c(f_n·p_c / T) - (f_n·p_{label})/T ), f normalized.

#define NS 1000000
#define NC 150
#define FD 128

static constexpr float INV_T = 1.0f / 0.15f;
// |f_hat · p_hat| <= 1  =>  |logit| <= 1/T. Fixed LSE shift: no online max needed,
// exp(x - MB) in [e^-13.3, 1] -- no overflow/underflow.
static constexpr float MB = 1.0f / 0.15f;

__global__ __launch_bounds__(256) void proto_ce_main(
    const float* __restrict__ feats,
    const int*   __restrict__ labels,
    const float* __restrict__ protos,
    double*      __restrict__ acc_out)
{
    const int n = blockIdx.x * 256 + threadIdx.x;
    float loss = 0.0f;
    if (n < NS) {
        // feature row -> 32 float4 in VGPRs
        float4 f[FD / 4];
        const float4* fptr = reinterpret_cast<const float4*>(feats + (size_t)n * FD);
#pragma unroll
        for (int i = 0; i < FD / 4; ++i) f[i] = fptr[i];

        float nrm = 0.0f;
#pragma unroll
        for (int i = 0; i < FD / 4; ++i)
            nrm += f[i].x * f[i].x + f[i].y * f[i].y + f[i].z * f[i].z + f[i].w * f[i].w;
        // ||f|| ~ sqrt(128) for N(0,1) features; never near eps.
        const float scale = rsqrtf(nrm) * INV_T;

        const int lbl = labels[n];
        float ssum = 0.0f;
        float picked = 0.0f;

        for (int c = 0; c < NC; ++c) {
            // c is wave-uniform -> compiler emits scalar loads (broadcast, no LDS needed)
            const float4* pp = reinterpret_cast<const float4*>(protos + c * FD);
            float d0 = 0.f, d1 = 0.f, d2 = 0.f, d3 = 0.f;
#pragma unroll
            for (int i = 0; i < FD / 4; ++i) {
                float4 p = pp[i];
                d0 += f[i].x * p.x;
                d1 += f[i].y * p.y;
                d2 += f[i].z * p.z;
                d3 += f[i].w * p.w;
            }
            const float x = ((d0 + d1) + (d2 + d3)) * scale;
            ssum += __expf(x - MB);
            picked = (c == lbl) ? x : picked;
        }
        loss = __logf(ssum) + MB - picked;
    }

    // wave-64 reduction, then one fp64 atomic per wave
#pragma unroll
    for (int off = 32; off > 0; off >>= 1)
        loss += __shfl_down(loss, off, 64);
    if ((threadIdx.x & 63) == 0)
        atomicAdd(acc_out, (double)loss);
}

__global__ void proto_ce_final(const double* __restrict__ acc, float* __restrict__ out)
{
    out[0] = (float)(acc[0] * (1.0 / (double)NS));
}

extern "C" void kernel_launch(void* const* d_in, const int* in_sizes, int n_in,
                              void* d_out, int out_size, void* d_ws, size_t ws_size,
                              hipStream_t stream)
{
    const float* feats  = (const float*)d_in[0];
    const int*   labels = (const int*)d_in[1];
    const float* protos = (const float*)d_in[2];

    double* acc = (double*)d_ws;
    hipMemsetAsync(acc, 0, sizeof(double), stream);

    const int blocks = (NS + 255) / 256;
    proto_ce_main<<<blocks, 256, 0, stream>>>(feats, labels, protos, acc);
    proto_ce_final<<<1, 1, 0, stream>>>(acc, (float*)d_out);
}

// Round 2
// 164.541 us; speedup vs baseline: 6.5955x; 6.5955x over previous
//
#include <hip/hip_runtime.h>

// proto-contrastive CE loss via bf16 MFMA.
// features [N=1e6, D=128] f32, labels [N] i32, prototypes [C=150, D=128] f32 (pre-normalized).
// out[0] = mean_n( logsumexp_c(f_n_hat · p_c / T) - (f_n_hat · p_label / T) )

#define NS 1000000
#define NC 150
#define NCP 160          // classes padded to 10 tiles of 16
#define FD 128

static constexpr float INV_T = 1.0f / 0.15f;
static constexpr float MB = 1.0f / 0.15f;   // fixed LSE shift; |logit| <= 1/T

typedef __attribute__((ext_vector_type(8))) short short8;
typedef __attribute__((ext_vector_type(4))) float f32x4;

__device__ __forceinline__ short f2bf(float x) {
    unsigned u = __builtin_bit_cast(unsigned, x);
    unsigned r = (u + 0x7fffu + ((u >> 16) & 1u)) >> 16;   // RNE
    return (short)r;
}

// ---- prep: fp32 protos [150][128] -> bf16 padded [160][128] in ws ----
__global__ __launch_bounds__(256) void proto_prep(
    const float* __restrict__ protos, unsigned short* __restrict__ dst)
{
    const int tid = threadIdx.x;
#pragma unroll 4
    for (int i = 0; i < (NCP * FD) / 256; ++i) {
        int idx = i * 256 + tid;
        int row = idx >> 7;
        int col = idx & 127;
        float v = (row < NC) ? protos[row * FD + col] : 0.0f;
        dst[idx] = (unsigned short)f2bf(v);
    }
}

// ---- main: per wave = 16 samples x 160 classes via 40 MFMAs ----
__global__ __launch_bounds__(256) void proto_ce_mfma(
    const float*          __restrict__ feats,
    const int*            __restrict__ labels,
    const unsigned short* __restrict__ protos_bf,  // [160][128] bf16 row-major
    double*               __restrict__ partials)
{
    __shared__ __align__(16) char lds[NCP * FD * 2];   // 40 KB, XOR-swizzled protos

    const int tid = threadIdx.x;

    // stage protos global->LDS with st-row swizzle: byte_in_row ^= (row&7)<<4
    {
        const uint4* src = (const uint4*)protos_bf;
#pragma unroll
        for (int i = 0; i < (NCP * FD * 2) / 16 / 256; ++i) {   // 10 iters
            int e8  = i * 256 + tid;            // 16B chunk id, 0..2559
            int row = e8 >> 4;                  // 16 chunks per 256B row
            int binr = (e8 & 15) << 4;
            int dst = row * 256 + (binr ^ ((row & 7) << 4));
            *(uint4*)(lds + dst) = src[e8];
        }
    }
    __syncthreads();

    const int lane = tid & 63;
    const int wave = tid >> 6;
    const int col  = lane & 15;     // sample within tile (B col) / class row (A row)
    const int grp  = lane >> 4;     // k-group
    const long base = ((long)blockIdx.x * 4 + wave) * 16;
    const long s    = base + col;

    // ---- load features: 8 floats per k-block at k = kb*32 + grp*8 ----
    float fv[32];
    const float* fp = feats + s * FD + grp * 8;
#pragma unroll
    for (int kb = 0; kb < 4; ++kb) {
        float4 a = *(const float4*)(fp + kb * 32);
        float4 b = *(const float4*)(fp + kb * 32 + 4);
        fv[kb*8+0]=a.x; fv[kb*8+1]=a.y; fv[kb*8+2]=a.z; fv[kb*8+3]=a.w;
        fv[kb*8+4]=b.x; fv[kb*8+5]=b.y; fv[kb*8+6]=b.z; fv[kb*8+7]=b.w;
    }

    // ---- per-sample L2 norm: local ssq + reduce across the 4 k-groups ----
    float ssq = 0.0f;
#pragma unroll
    for (int i = 0; i < 32; ++i) ssq += fv[i] * fv[i];
    ssq += __shfl_xor(ssq, 16, 64);
    ssq += __shfl_xor(ssq, 32, 64);
    const float scl = rsqrtf(fmaxf(ssq, 1e-24f));

    // ---- convert to bf16 B-fragments: B[k][col], k = kb*32 + grp*8 + j ----
    short8 bfrag[4];
#pragma unroll
    for (int kb = 0; kb < 4; ++kb)
#pragma unroll
        for (int j = 0; j < 8; ++j)
            bfrag[kb][j] = f2bf(fv[kb*8 + j] * scl);

    // ---- MFMA: acc[t] = P_tile_t x Fhat, D[class][sample] ----
    f32x4 acc[10];
#pragma unroll
    for (int t = 0; t < 10; ++t) acc[t] = (f32x4){0.f, 0.f, 0.f, 0.f};

#pragma unroll
    for (int kb = 0; kb < 4; ++kb) {
#pragma unroll
        for (int t = 0; t < 10; ++t) {
            int arow  = t * 16 + col;
            int abyte = arow * 256 + ((kb * 64 + grp * 16) ^ ((arow & 7) << 4));
            short8 af = *(const short8*)(lds + abyte);
            acc[t] = __builtin_amdgcn_mfma_f32_16x16x32_bf16(af, bfrag[kb], acc[t], 0, 0, 0);
        }
    }

    // ---- epilogue: lane holds 40 class-logits for sample `col` ----
    const int lbl = labels[base + col];
    float ssum = 0.0f, picked = 0.0f;
#pragma unroll
    for (int t = 0; t < 10; ++t) {
#pragma unroll
        for (int r = 0; r < 4; ++r) {
            int cls = t * 16 + grp * 4 + r;
            float x = acc[t][r] * INV_T;
            float e = __expf(x - MB);
            bool valid = (cls < NC);
            ssum   += valid ? e : 0.0f;
            picked += (valid && cls == lbl) ? x : 0.0f;
        }
    }
    // combine the 4 k-groups (each holds 40 of the 160 classes)
    ssum   += __shfl_xor(ssum, 16, 64);   ssum   += __shfl_xor(ssum, 32, 64);
    picked += __shfl_xor(picked, 16, 64); picked += __shfl_xor(picked, 32, 64);

    float loss = __logf(ssum) + MB - picked;

    // sum the 16 samples of this wave (all 4 groups hold identical copies)
    loss += __shfl_xor(loss, 1, 64);
    loss += __shfl_xor(loss, 2, 64);
    loss += __shfl_xor(loss, 4, 64);
    loss += __shfl_xor(loss, 8, 64);
    // lane 0 now has 4x the 16-sample sum? No: groups identical -> xor over
    // 1,2,4,8 sums within each 16-lane group only. lane 0 = sum of samples 0..15.
    if (lane == 0)
        atomicAdd(&partials[blockIdx.x & 255], (double)loss);
}

__global__ __launch_bounds__(256) void proto_ce_final(
    const double* __restrict__ partials, float* __restrict__ out)
{
    const int tid = threadIdx.x;
    double v = partials[tid];
#pragma unroll
    for (int off = 32; off > 0; off >>= 1)
        v += __shfl_down(v, off, 64);
    __shared__ double w[4];
    if ((tid & 63) == 0) w[tid >> 6] = v;
    __syncthreads();
    if (tid == 0)
        out[0] = (float)((w[0] + w[1] + w[2] + w[3]) * (1.0 / (double)NS));
}

extern "C" void kernel_launch(void* const* d_in, const int* in_sizes, int n_in,
                              void* d_out, int out_size, void* d_ws, size_t ws_size,
                              hipStream_t stream)
{
    const float* feats  = (const float*)d_in[0];
    const int*   labels = (const int*)d_in[1];
    const float* protos = (const float*)d_in[2];

    unsigned short* protos_bf = (unsigned short*)d_ws;                 // 40960 B
    double* partials = (double*)((char*)d_ws + NCP * FD * 2);          // 2048 B

    hipMemsetAsync(partials, 0, 256 * sizeof(double), stream);
    proto_prep<<<1, 256, 0, stream>>>(protos, protos_bf);
    proto_ce_mfma<<<NS / 64, 256, 0, stream>>>(feats, labels, protos_bf, partials);
    proto_ce_final<<<1, 256, 0, stream>>>(partials, (float*)d_out);
}